// Round 9
// baseline (145.947 us; speedup 1.0000x reference)
//
#include <hip/hip_runtime.h>
#include <math.h>

#define BATCH  256
#define NQ     1000
#define NQH    500      // rows per half (81*500 % 4 == 0 -> clean chunk split)
#define NC     81
#define QC     81000
#define TOPK   100
#define NBINS  4096
#define CAP    2048
#define NT1    1024
#define NT2    256

// Precise logistic, matching jax.nn.sigmoid (per-q factors + final candidates
// -> output scores bit-identical to the known-absmax=0 kernel).
__device__ __forceinline__ float sigmoidf(float x) {
    if (x >= 0.f) return 1.f / (1.f + expf(-x));
    float e = expf(x);
    return e / (1.f + e);
}

// Fast branch-free logistic (~1e-5 rel err; key = P*fast_sig <= P always).
__device__ __forceinline__ float fast_sig(float x) {
    return __builtin_amdgcn_rcpf(1.f + __expf(-x));
}

struct Smem1 {
    float    P[NQH];      // exp(-obj)*(1-sig(unk))  — per-row upper bound
    float    Pm2[NQH];    // row skip bound (max with next row in half)
    float    op[NQH];     // exp(-obj)               (precise)
    float    omun[NQH];   // 1 - sig(unk)            (precise)
    float    last[NQH];   // exp(-obj)*sig(unk)      class 80 (precise)
    unsigned hist[NBINS];
    uint2    cand[CAP];   // .x = precise score bits, .y = batch-flat index
    int      rowlist[NQH];// global row ids
    unsigned nrows;
    unsigned cnt;
    unsigned thr;
};

// Largest bin t with |{keys in bins >= t}| >= TOPK. Wave-0 shuffle suffix scan.
// Coarse reads lane-rotated -> 2 lanes/bank (free); fine reads stride-1.
__device__ unsigned scan_threshold(Smem1& s, int tid) {
    __syncthreads();
    if (tid < 64) {
        unsigned c = 0;
        #pragma unroll
        for (int j = 0; j < 64; ++j) {
            int jj = (j + tid) & 63;
            c += s.hist[tid * 64 + jj];
        }
        unsigned ssum = c;
        #pragma unroll
        for (int off = 1; off < 64; off <<= 1) {
            unsigned o = __shfl_down(ssum, off, 64);
            if (tid + off < 64) ssum += o;
        }
        unsigned long long bal = __ballot(ssum >= TOPK);
        int cb = 63 - __clzll(bal);
        unsigned tb = 0;
        if (cb >= 0) {
            unsigned S_cb = __shfl(ssum, cb, 64);
            unsigned c_cb = __shfl(c, cb, 64);
            unsigned acc  = S_cb - c_cb;
            unsigned fs = s.hist[cb * 64 + tid];
            #pragma unroll
            for (int off = 1; off < 64; off <<= 1) {
                unsigned o = __shfl_down(fs, off, 64);
                if (tid + off < 64) fs += o;
            }
            unsigned long long bal2 = __ballot(acc + fs >= TOPK);
            int fb = 63 - __clzll(bal2);
            tb = (unsigned)(cb * 64 + fb);
        }
        if (tid == 0) s.thr = tb;
    }
    __syncthreads();
    return s.thr;
}

template <bool COLLECT>
__device__ __forceinline__ void proc_chunk(Smem1& s, const float4& v4, int q,
                                           int c, int r0, unsigned thbits) {
    float xs[4] = {v4.x, v4.y, v4.z, v4.w};
    #pragma unroll
    for (int k = 0; k < 4; ++k) {
        int ck = c + k, qk = q;
        if (ck >= NC) { ck -= NC; ++qk; }     // never crosses the half boundary
        if (ck < 60) {                        // 60..79 invalid; 80 via collect80
            int lk = qk - r0;
            unsigned u = __float_as_uint(s.P[lk] * fast_sig(xs[k]));
            if (u >= thbits) {
                if (!COLLECT) {
                    atomicAdd(&s.hist[u >> 19], 1u);
                } else {
                    float pv = (s.op[lk] * sigmoidf(xs[k])) * s.omun[lk]; // ref order
                    unsigned p = atomicAdd(&s.cnt, 1u);
                    if (p < CAP)
                        s.cand[p] = make_uint2(__float_as_uint(pv),
                                               (unsigned)(qk * NC + ck));
                }
            }
        }
    }
}

__device__ void build_rows(Smem1& s, unsigned thbits, int r0, int tid) {
    __syncthreads();
    if (tid == 0) s.nrows = 0;
    __syncthreads();
    if (tid < NQH)
        if (__float_as_uint(s.Pm2[tid]) >= thbits)
            s.rowlist[atomicAdd(&s.nrows, 1u)] = r0 + tid;
    __syncthreads();
}

// Dense walk over owned chunks of listed rows. Row q owns chunks
// [ceil(81q/4), ceil(81(q+1)/4)) — disjoint, complete, half-contained.
template <bool COLLECT>
__device__ void scan_rows(Smem1& s, const float4* __restrict__ lg4,
                          unsigned thbits, int r0, int tid) {
    const int total = (int)s.nrows * 21;
    for (int idx = tid; idx < total; idx += NT1) {
        int r  = idx / 21;
        int j  = idx - r * 21;
        int q  = s.rowlist[r];
        int e0 = NC * q;
        int i4 = ((e0 + 3) >> 2) + j;
        if (4 * i4 < e0 + NC) {
            float4 v4 = lg4[i4];
            proc_chunk<COLLECT>(s, v4, q, 4 * i4 - e0, r0, thbits);
        }
    }
}

__device__ void collect80(Smem1& s, unsigned thbits, int r0, int tid) {
    if (tid < NQH) {
        unsigned u = __float_as_uint(s.last[tid]);
        if (u >= thbits) {
            unsigned p = atomicAdd(&s.cnt, 1u);
            if (p < CAP)
                s.cand[p] = make_uint2(u, (unsigned)((r0 + tid) * NC + 80));
        }
    }
}

// Stage 1: one block per (batch, half). Exact top-100 of the half -> ws.
__global__ __launch_bounds__(NT1) void stage1_kernel(
    const float* __restrict__ logits,   // [B, Q, C]
    const float* __restrict__ obj,      // [B, Q]
    const float* __restrict__ unk,      // [B, Q]
    uint2* __restrict__ ws)             // [B*2][TOPK] (score_bits, flat_idx)
{
    __shared__ Smem1 s;
    const int blk = blockIdx.x;
    const int b   = blk >> 1;
    const int r0  = (blk & 1) * NQH;    // first global row of this half
    const int tid = threadIdx.x;
    const float4* lg4 = (const float4*)(logits + (size_t)b * QC);

    // ---- init ----
    *(uint4*)&s.hist[tid * 4] = make_uint4(0u, 0u, 0u, 0u);
    if (tid == 0) s.cnt = 0;
    if (tid < NQH) {
        int q = r0 + tid;
        float opv = expf(-obj[b * NQ + q]);
        float un  = sigmoidf(unk[b * NQ + q]);
        float om  = 1.f - un;
        s.op[tid] = opv; s.omun[tid] = om; s.P[tid] = opv * om;
        s.last[tid] = opv * un;
    }
    __syncthreads();

    // row bounds + class-80 histogram (no logit reads)
    if (tid < NQH) {
        float pm = s.P[tid];
        if (tid + 1 < NQH) pm = fmaxf(pm, s.P[tid + 1]);
        s.Pm2[tid] = pm;
        atomicAdd(&s.hist[__float_as_uint(s.last[tid]) >> 19], 1u);
    }

    // provisional threshold from class-80 alone (lower bound on final tF)
    unsigned t0 = scan_threshold(s, tid);

    // pass 1: histogram over surviving rows
    build_rows(s, t0 << 19, r0, tid);
    scan_rows<false>(s, lg4, t0 << 19, r0, tid);

    // exact final threshold for this half
    unsigned tF = scan_threshold(s, tid);

    // pass 2: collect at tF-1 bin floor (provable top-100 superset of half)
    unsigned thC = ((tF >= 1) ? tF - 1 : 0) << 19;
    build_rows(s, thC, r0, tid);
    scan_rows<true>(s, lg4, thC, r0, tid);
    collect80(s, thC, r0, tid);
    __syncthreads();

    if (s.cnt > CAP) {                  // massive-tie pathology only
        __syncthreads();
        if (tid == 0) s.cnt = 0;
        __syncthreads();
        scan_rows<true>(s, lg4, tF << 19, r0, tid);
        collect80(s, tF << 19, r0, tid);
        __syncthreads();
    }

    const int m = (int)min(s.cnt, (unsigned)CAP);   // m >= 100 always

    // rank (uint bit order == value order; tie-break lower flat idx first)
    uint2* wout = ws + (size_t)blk * TOPK;
    for (int i = tid; i < m; i += NT1) {
        uint2 ci = s.cand[i];
        int r = 0;
        for (int j = 0; j < m; ++j) {
            uint2 cj = s.cand[j];       // uniform j -> LDS broadcast
            r += (cj.x > ci.x) || (cj.x == ci.x && cj.y < ci.y);
        }
        if (r < TOPK) wout[r] = ci;
    }
}

// Stage 2: merge the two per-half top-100 lists exactly; box epilogue.
__global__ __launch_bounds__(NT2) void stage2_kernel(
    const uint2* __restrict__ ws,       // [B*2][TOPK]
    const float* __restrict__ boxes,    // [B, Q, 4] cx cy w h
    const float* __restrict__ tsz,      // [B, 2]  (h, w)
    float* __restrict__ out)            // scores[B*K] | labels[B*K] | boxes[B*K*4]
{
    __shared__ uint2 cand[2 * TOPK];
    const int b   = blockIdx.x;
    const int tid = threadIdx.x;

    if (tid < 2 * TOPK) cand[tid] = ws[(size_t)b * 2 * TOPK + tid];
    __syncthreads();

    const float* bx = boxes + (size_t)b * NQ * 4;
    const float img_h = tsz[b * 2 + 0];
    const float img_w = tsz[b * 2 + 1];
    float* o_sc = out + (size_t)b * TOPK;
    float* o_lb = out + (size_t)BATCH * TOPK + (size_t)b * TOPK;
    float* o_bx = out + (size_t)2 * BATCH * TOPK + (size_t)b * TOPK * 4;

    if (tid < 2 * TOPK) {
        uint2 ci = cand[tid];
        int r = 0;
        for (int j = 0; j < 2 * TOPK; ++j) {
            uint2 cj = cand[j];
            r += (cj.x > ci.x) || (cj.x == ci.x && cj.y < ci.y);
        }
        if (r < TOPK) {
            int ei = (int)ci.y;
            o_sc[r] = __uint_as_float(ci.x);
            o_lb[r] = (float)(ei % NC);
            int q = ei / NC;
            float cx = bx[q * 4 + 0];
            float cy = bx[q * 4 + 1];
            float w  = bx[q * 4 + 2];
            float h  = bx[q * 4 + 3];
            o_bx[r * 4 + 0] = (cx - 0.5f * w) * img_w;
            o_bx[r * 4 + 1] = (cy - 0.5f * h) * img_h;
            o_bx[r * 4 + 2] = (cx + 0.5f * w) * img_w;
            o_bx[r * 4 + 3] = (cy + 0.5f * h) * img_h;
        }
    }
}

extern "C" void kernel_launch(void* const* d_in, const int* in_sizes, int n_in,
                              void* d_out, int out_size, void* d_ws, size_t ws_size,
                              hipStream_t stream) {
    const float* pred_logits = (const float*)d_in[0];
    const float* pred_obj    = (const float*)d_in[1];
    const float* pred_boxes  = (const float*)d_in[2];
    const float* pred_unk    = (const float*)d_in[3];
    const float* target_sz   = (const float*)d_in[4];
    float* out = (float*)d_out;
    uint2* ws  = (uint2*)d_ws;          // 512*100*8 B = 400 KB used

    stage1_kernel<<<BATCH * 2, NT1, 0, stream>>>(pred_logits, pred_obj,
                                                 pred_unk, ws);
    stage2_kernel<<<BATCH, NT2, 0, stream>>>(ws, pred_boxes, target_sz, out);
}

// Round 10
// 134.773 us; speedup vs baseline: 1.0829x; 1.0829x over previous
//
#include <hip/hip_runtime.h>
#include <math.h>

#define BATCH  256
#define NQ     1000
#define NC     81
#define QC     81000
#define TOPK   100
#define NBINS  4096
#define CAP    6144
#define CAP2   1024
#define NT     1024
#define MARGIN 4096u   // bit-space sliver below a bin floor (~5e-4 rel) covering
                       // fast-vs-precise score error (~few*1e-6) with 100x slack

// Precise logistic, matching jax.nn.sigmoid (per-q factors + final candidates
// -> output scores bit-identical to the known-absmax=0 kernel).
__device__ __forceinline__ float sigmoidf(float x) {
    if (x >= 0.f) return 1.f / (1.f + expf(-x));
    float e = expf(x);
    return e / (1.f + e);
}

// Fast branch-free logistic (<=1 always; key = P*fast_sig <= P).
__device__ __forceinline__ float fast_sig(float x) {
    return __builtin_amdgcn_rcpf(1.f + __expf(-x));
}

struct Smem {
    float    P[NQ];       // exp(-obj)*(1-sig(unk))  — per-row upper bound
    float    Pm2[NQ];     // max(P[q], P[q+1])       — row skip bound
    float    op[NQ];      // exp(-obj)               (precise)
    float    omun[NQ];    // 1 - sig(unk)            (precise)
    float    last[NQ];    // exp(-obj)*sig(unk)      class 80 (precise)
    unsigned hist[NBINS];
    uint2    cand[CAP];   // .x = approx key bits, .y = flat index
    uint2    cand2[CAP2]; // .x = precise score bits, .y = flat index
    int      rowlist[NQ];
    unsigned nrows;
    unsigned cnt;
    unsigned cnt2;
    unsigned thr;
};

// Largest bin t with |{keys in bins >= t}| >= TOPK. Wave-0 shuffle suffix scan.
// Coarse reads lane-rotated -> 2 lanes/bank (free, m136); fine reads stride-1.
__device__ unsigned scan_threshold(Smem& s, int tid) {
    __syncthreads();
    if (tid < 64) {
        unsigned c = 0;
        #pragma unroll
        for (int j = 0; j < 64; ++j) {
            int jj = (j + tid) & 63;
            c += s.hist[tid * 64 + jj];
        }
        unsigned ssum = c;
        #pragma unroll
        for (int off = 1; off < 64; off <<= 1) {
            unsigned o = __shfl_down(ssum, off, 64);
            if (tid + off < 64) ssum += o;
        }
        unsigned long long bal = __ballot(ssum >= TOPK);
        int cb = 63 - __clzll(bal);
        unsigned tb = 0;
        if (cb >= 0) {
            unsigned S_cb = __shfl(ssum, cb, 64);
            unsigned c_cb = __shfl(c, cb, 64);
            unsigned acc  = S_cb - c_cb;          // count strictly above coarse bin
            unsigned fs = s.hist[cb * 64 + tid];
            #pragma unroll
            for (int off = 1; off < 64; off <<= 1) {
                unsigned o = __shfl_down(fs, off, 64);
                if (tid + off < 64) fs += o;
            }
            unsigned long long bal2 = __ballot(acc + fs >= TOPK);
            int fb = 63 - __clzll(bal2);
            tb = (unsigned)(cb * 64 + fb);
        }
        if (tid == 0) s.thr = tb;
    }
    __syncthreads();
    return s.thr;
}

// Compact list of rows whose bound can reach thbits.
__device__ void build_rows(Smem& s, unsigned thbits, int tid) {
    __syncthreads();
    if (tid == 0) s.nrows = 0;
    __syncthreads();
    for (int q = tid; q < NQ; q += NT)
        if (__float_as_uint(s.Pm2[q]) >= thbits)
            s.rowlist[atomicAdd(&s.nrows, 1u)] = q;
    __syncthreads();
}

// FUSED walk over owned chunks of listed rows: histogram + (key,idx) append
// for every element with key >= thbits. Row q owns chunks
// [ceil(81q/4), ceil(81(q+1)/4)) — disjoint & complete.
__device__ void scan_fused(Smem& s, const float4* __restrict__ lg4,
                           unsigned thbits, int tid) {
    const int total = (int)s.nrows * 21;
    for (int idx = tid; idx < total; idx += NT) {
        int r  = idx / 21;
        int j  = idx - r * 21;
        int q  = s.rowlist[r];
        int e0 = NC * q;
        int i4 = ((e0 + 3) >> 2) + j;
        if (4 * i4 < e0 + NC) {
            float4 v4 = lg4[i4];
            int c = 4 * i4 - e0;
            float xs[4] = {v4.x, v4.y, v4.z, v4.w};
            #pragma unroll
            for (int k = 0; k < 4; ++k) {
                int ck = c + k, qk = q;
                if (ck >= NC) { ck -= NC; ++qk; }
                if (ck < 60) {                   // 60..79 invalid; 80 separate
                    unsigned u = __float_as_uint(s.P[qk] * fast_sig(xs[k]));
                    if (u >= thbits) {
                        atomicAdd(&s.hist[u >> 19], 1u);
                        unsigned p = atomicAdd(&s.cnt, 1u);
                        if (p < CAP)
                            s.cand[p] = make_uint2(u, (unsigned)(qk * NC + ck));
                    }
                }
            }
        }
    }
}

// Fallback: precise collection into cand2 by row walk (rare path).
__device__ void collect_precise(Smem& s, const float4* __restrict__ lg4,
                                unsigned thbits, int tid) {
    const int total = (int)s.nrows * 21;
    for (int idx = tid; idx < total; idx += NT) {
        int r  = idx / 21;
        int j  = idx - r * 21;
        int q  = s.rowlist[r];
        int e0 = NC * q;
        int i4 = ((e0 + 3) >> 2) + j;
        if (4 * i4 < e0 + NC) {
            float4 v4 = lg4[i4];
            int c = 4 * i4 - e0;
            float xs[4] = {v4.x, v4.y, v4.z, v4.w};
            #pragma unroll
            for (int k = 0; k < 4; ++k) {
                int ck = c + k, qk = q;
                if (ck >= NC) { ck -= NC; ++qk; }
                if (ck < 60) {
                    unsigned u = __float_as_uint(s.P[qk] * fast_sig(xs[k]));
                    if (u >= thbits) {
                        float pv = (s.op[qk] * sigmoidf(xs[k])) * s.omun[qk];
                        unsigned p = atomicAdd(&s.cnt2, 1u);
                        if (p < CAP2)
                            s.cand2[p] = make_uint2(__float_as_uint(pv),
                                                    (unsigned)(qk * NC + ck));
                    }
                }
            }
        }
    }
}

__device__ void collect80_approx(Smem& s, unsigned thbits, int tid) {
    for (int q = tid; q < NQ; q += NT) {
        unsigned u = __float_as_uint(s.last[q]);   // approx == precise for c=80
        if (u >= thbits) {
            unsigned p = atomicAdd(&s.cnt, 1u);
            if (p < CAP) s.cand[p] = make_uint2(u, (unsigned)(q * NC + 80));
        }
    }
}

__device__ void collect80_precise(Smem& s, unsigned thbits, int tid) {
    for (int q = tid; q < NQ; q += NT) {
        unsigned u = __float_as_uint(s.last[q]);
        if (u >= thbits) {
            unsigned p = atomicAdd(&s.cnt2, 1u);
            if (p < CAP2) s.cand2[p] = make_uint2(u, (unsigned)(q * NC + 80));
        }
    }
}

__global__ __launch_bounds__(NT) void postprocess_kernel(
    const float* __restrict__ logits,   // [B, Q, C]
    const float* __restrict__ obj,      // [B, Q]
    const float* __restrict__ boxes,    // [B, Q, 4] cx cy w h
    const float* __restrict__ unk,      // [B, Q]
    const float* __restrict__ tsz,      // [B, 2]  (h, w)
    float* __restrict__ out)            // scores[B*K] | labels[B*K] | boxes[B*K*4]
{
    __shared__ Smem s;
    const int b   = blockIdx.x;
    const int tid = threadIdx.x;
    const float*  lgf = logits + (size_t)b * QC;
    const float4* lg4 = (const float4*)lgf;

    // ---- init ----
    *(uint4*)&s.hist[tid * 4] = make_uint4(0u, 0u, 0u, 0u);
    if (tid == 0) { s.cnt = 0; s.cnt2 = 0; }
    for (int q = tid; q < NQ; q += NT) {
        float op = expf(-obj[b * NQ + q]);
        float un = sigmoidf(unk[b * NQ + q]);
        float om = 1.f - un;
        s.op[q] = op; s.omun[q] = om; s.P[q] = op * om; s.last[q] = op * un;
    }
    __syncthreads();

    // row bounds + class-80 histogram (no logit reads needed)
    for (int q = tid; q < NQ; q += NT) {
        float pm = s.P[q];
        if (q + 1 < NQ) pm = fmaxf(pm, s.P[q + 1]);
        s.Pm2[q] = pm;
        atomicAdd(&s.hist[__float_as_uint(s.last[q]) >> 19], 1u);
    }

    // provisional threshold from class-80 alone (lower bound on final tF).
    unsigned t0   = scan_threshold(s, tid);
    unsigned th0m = t0 ? ((t0 << 19) - MARGIN) : 0;   // bin floor minus sliver

    // ---- single fused walk: histogram + approx-candidate append ----
    // Rowlist at th0m is (within the negligible sliver) the same set as at
    // t0's bin floor -> FETCH identical to the two-walk variant's pass 1.
    build_rows(s, th0m, tid);
    scan_fused(s, lg4, th0m, tid);
    collect80_approx(s, th0m, tid);
    __syncthreads();

    // Final threshold. Bins >= t0 are complete (sliver counts land in bin
    // t0-1 and below); cum(t0) >= TOPK already, so the scan returns tF >= t0.
    unsigned tF   = scan_threshold(s, tid);
    unsigned thCm = tF ? ((tF << 19) - MARGIN) : 0;

    unsigned total = s.cnt;
    if (total <= CAP) {
        // ---- compact from LDS; precise rescore of ~150-300 (L2-hot reload).
        // Any true top-100 element has approx key >= binfloor(tF)*(1-4e-5),
        // i.e. bits >= thCm -> provable superset.
        for (int i = tid; i < (int)total; i += NT) {
            uint2 cd = s.cand[i];
            if (cd.x >= thCm) {
                unsigned q = cd.y / NC;
                unsigned c = cd.y - q * NC;
                float pv;
                if (c == 80) pv = s.last[q];
                else         pv = (s.op[q] * sigmoidf(lgf[cd.y])) * s.omun[q];
                unsigned p = atomicAdd(&s.cnt2, 1u);
                if (p < CAP2) s.cand2[p] = make_uint2(__float_as_uint(pv), cd.y);
            }
        }
        __syncthreads();
    }
    if (total > CAP || s.cnt2 > CAP2) {
        // rare fallback: precise re-collect by walk at thCm (rowlist built at
        // th0m <= thCm is a superset — still valid).
        __syncthreads();
        if (tid == 0) s.cnt2 = 0;
        __syncthreads();
        collect_precise(s, lg4, thCm, tid);
        collect80_precise(s, thCm, tid);
        __syncthreads();
        if (s.cnt2 > CAP2) {                 // massive-tie pathology only
            __syncthreads();
            if (tid == 0) s.cnt2 = 0;
            __syncthreads();
            collect_precise(s, lg4, tF << 19, tid);
            collect80_precise(s, tF << 19, tid);
            __syncthreads();
        }
    }

    const int m = (int)min(s.cnt2, (unsigned)CAP2);

    // ---- rank (exact; scores >= 0 so uint bit order == value order;
    //      tie-break lower flat index first, like lax.top_k) ----
    const float* bx = boxes + (size_t)b * NQ * 4;
    const float img_h = tsz[b * 2 + 0];
    const float img_w = tsz[b * 2 + 1];
    float* o_sc = out + (size_t)b * TOPK;
    float* o_lb = out + (size_t)BATCH * TOPK + (size_t)b * TOPK;
    float* o_bx = out + (size_t)2 * BATCH * TOPK + (size_t)b * TOPK * 4;

    for (int i = tid; i < m; i += NT) {
        uint2 ci = s.cand2[i];
        int r = 0;
        for (int j = 0; j < m; ++j) {
            uint2 cj = s.cand2[j];      // uniform j -> LDS broadcast, no conflict
            r += (cj.x > ci.x) || (cj.x == ci.x && cj.y < ci.y);
        }
        if (r < TOPK) {
            int ei = (int)ci.y;
            o_sc[r] = __uint_as_float(ci.x);
            o_lb[r] = (float)(ei % NC);
            int q = ei / NC;
            float cx = bx[q * 4 + 0];
            float cy = bx[q * 4 + 1];
            float w  = bx[q * 4 + 2];
            float h  = bx[q * 4 + 3];
            o_bx[r * 4 + 0] = (cx - 0.5f * w) * img_w;
            o_bx[r * 4 + 1] = (cy - 0.5f * h) * img_h;
            o_bx[r * 4 + 2] = (cx + 0.5f * w) * img_w;
            o_bx[r * 4 + 3] = (cy + 0.5f * h) * img_h;
        }
    }
}

extern "C" void kernel_launch(void* const* d_in, const int* in_sizes, int n_in,
                              void* d_out, int out_size, void* d_ws, size_t ws_size,
                              hipStream_t stream) {
    const float* pred_logits = (const float*)d_in[0];
    const float* pred_obj    = (const float*)d_in[1];
    const float* pred_boxes  = (const float*)d_in[2];
    const float* pred_unk    = (const float*)d_in[3];
    const float* target_sz   = (const float*)d_in[4];
    float* out = (float*)d_out;
    postprocess_kernel<<<BATCH, NT, 0, stream>>>(
        pred_logits, pred_obj, pred_boxes, pred_unk, target_sz, out);
}